// Round 15
// baseline (521.884 us; speedup 1.0000x reference)
//
#include <hip/hip_runtime.h>
#include <cstddef>

#define D_M 1024
#define NH 16
#define HD 64
#define FFD 4096
#define SQ 2048
#define BB 2
#define TOK (BB*SQ)   // 4096
#define EPS 1e-5f

typedef __attribute__((ext_vector_type(8))) short bf16x8;
typedef __attribute__((ext_vector_type(4))) float f32x4;

__device__ inline unsigned short f32_bf16_rne(float f) {
  unsigned int u = __float_as_uint(f);
  unsigned int r = (u + 0x7fffu + ((u >> 16) & 1u)) >> 16;
  return (unsigned short)r;
}

__device__ inline float wave_sum(float v) {
  #pragma unroll
  for (int m = 32; m >= 1; m >>= 1) v += __shfl_xor(v, m);
  return v;
}

// ---------------- fp32 -> bf16 (RNE), vectorized ----------------
__global__ __launch_bounds__(256)
void convert_bf16_k(const float* __restrict__ src, unsigned short* __restrict__ dst, int n4) {
  int i = blockIdx.x * 256 + threadIdx.x;
  if (i >= n4) return;
  float4 v = ((const float4*)src)[i];
  ushort4 h;
  h.x = f32_bf16_rne(v.x); h.y = f32_bf16_rne(v.y);
  h.z = f32_bf16_rne(v.z); h.w = f32_bf16_rne(v.w);
  ((ushort4*)dst)[i] = h;
}

// ---------------- fp32 -> bf16, 2 tensors in one launch ----------------
__global__ __launch_bounds__(256)
void convert2_bf16_k(const float* __restrict__ s0, unsigned short* __restrict__ d0,
                     const float* __restrict__ s1, unsigned short* __restrict__ d1, int n4) {
  const float* src = blockIdx.y ? s1 : s0;
  unsigned short* dst = blockIdx.y ? d1 : d0;
  int i = blockIdx.x * 256 + threadIdx.x;
  if (i >= n4) return;
  float4 v = ((const float4*)src)[i];
  ushort4 h;
  h.x = f32_bf16_rne(v.x); h.y = f32_bf16_rne(v.y);
  h.z = f32_bf16_rne(v.z); h.w = f32_bf16_rne(v.w);
  ((ushort4*)dst)[i] = h;
}

// ---------------- 4x W[1024][1024] fp32 -> WT bf16 [N][K], one launch ----------------
__global__ __launch_bounds__(256)
void transp4_k(const float* __restrict__ W0, const float* __restrict__ W1_,
               const float* __restrict__ W2_, const float* __restrict__ W3,
               unsigned short* __restrict__ h0, unsigned short* __restrict__ h1,
               unsigned short* __restrict__ h2, unsigned short* __restrict__ h3) {
  const float* W; unsigned short* hT;
  switch (blockIdx.z) {
    case 0: W = W0; hT = h0; break;
    case 1: W = W1_; hT = h1; break;
    case 2: W = W2_; hT = h2; break;
    default: W = W3; hT = h3; break;
  }
  __shared__ float tile[64][65];
  const int bn = blockIdx.x * 64;
  const int bk = blockIdx.y * 64;
  const int t = threadIdx.x;
  #pragma unroll
  for (int i = 0; i < 4; ++i) {
    int r = (t >> 4) + i * 16, c = (t & 15) * 4;
    float4 v = *(const float4*)&W[(size_t)(bk + r) * D_M + bn + c];
    tile[r][c] = v.x; tile[r][c + 1] = v.y; tile[r][c + 2] = v.z; tile[r][c + 3] = v.w;
  }
  __syncthreads();
  #pragma unroll
  for (int i = 0; i < 4; ++i) {
    int n = (t >> 4) + i * 16, k = (t & 15) * 4;
    ushort4 h;
    h.x = f32_bf16_rne(tile[k][n]);     h.y = f32_bf16_rne(tile[k + 1][n]);
    h.z = f32_bf16_rne(tile[k + 2][n]); h.w = f32_bf16_rne(tile[k + 3][n]);
    *(ushort4*)&hT[(size_t)(bn + n) * D_M + bk + k] = h;
  }
}

// ---------------- merged QKV GEMM, bf16, one A-tile for 3 weight sets ----------------
__global__ __launch_bounds__(256)
void qkv_gemm_k(const unsigned short* __restrict__ xh_g,
                const unsigned short* __restrict__ Bqh, const unsigned short* __restrict__ Bkh,
                const unsigned short* __restrict__ Bvh,
                const float* __restrict__ bq, const float* __restrict__ bk, const float* __restrict__ bv,
                unsigned short* __restrict__ qh, unsigned short* __restrict__ kh,
                unsigned short* __restrict__ vth) {
  constexpr int LDK = 40;
  __shared__ unsigned short Ah[64 * LDK];
  __shared__ unsigned short Bh[3][128 * LDK];
  const int tid = threadIdx.x;
  const int wave = tid >> 6, lane = tid & 63;
  const int wm = (wave >> 1) * 32, wn = (wave & 1) * 64;
  const int bn = blockIdx.x * 128, bm = blockIdx.y * 64;
  const int K = D_M;

  f32x4 acc[3][2][4] = {};
  const int sr = tid >> 2, sk = (tid & 3) * 8;
  const int l15 = lane & 15, k8 = (lane >> 4) * 8;

  const unsigned short* Bhp[3] = {Bqh, Bkh, Bvh};

  for (int k0 = 0; k0 < K; k0 += 32) {
    *(uint4*)&Ah[sr * LDK + sk] = *(const uint4*)&xh_g[(size_t)(bm + sr) * K + k0 + sk];
    #pragma unroll
    for (int s = 0; s < 3; ++s) {
      #pragma unroll
      for (int c = 0; c < 2; ++c) {
        int r = sr + c * 64;
        *(uint4*)&Bh[s][r * LDK + sk] = *(const uint4*)&Bhp[s][(size_t)(bn + r) * K + k0 + sk];
      }
    }
    __syncthreads();
    bf16x8 af[2];
    #pragma unroll
    for (int m = 0; m < 2; ++m)
      af[m] = *(bf16x8*)&Ah[(wm + m * 16 + l15) * LDK + k8];
    #pragma unroll
    for (int s = 0; s < 3; ++s) {
      #pragma unroll
      for (int n = 0; n < 4; ++n) {
        bf16x8 b0 = *(bf16x8*)&Bh[s][(wn + n * 16 + l15) * LDK + k8];
        #pragma unroll
        for (int m = 0; m < 2; ++m) {
          if (s == 2) {  // V: unswapped (D col = weight col, rows = token)
            acc[s][m][n] = __builtin_amdgcn_mfma_f32_16x16x32_bf16(af[m], b0, acc[s][m][n], 0, 0, 0);
          } else {       // Q,K: swapped (D col = token, rows = weight col)
            acc[s][m][n] = __builtin_amdgcn_mfma_f32_16x16x32_bf16(b0, af[m], acc[s][m][n], 0, 0, 0);
          }
        }
      }
    }
    __syncthreads();
  }
  const int kq4 = (lane >> 4) * 4;
  #pragma unroll
  for (int s = 0; s < 2; ++s) {
    const float* bias = (s == 0) ? bq : bk;
    unsigned short* oh = (s == 0) ? qh : kh;
    #pragma unroll
    for (int n = 0; n < 4; ++n) {
      int colb = bn + wn + n * 16 + kq4;
      float4 bv4 = *(const float4*)&bias[colb];
      #pragma unroll
      for (int m = 0; m < 2; ++m) {
        int tok = bm + wm + m * 16 + l15;
        ushort4 h;
        h.x = f32_bf16_rne(acc[s][m][n][0] + bv4.x);
        h.y = f32_bf16_rne(acc[s][m][n][1] + bv4.y);
        h.z = f32_bf16_rne(acc[s][m][n][2] + bv4.z);
        h.w = f32_bf16_rne(acc[s][m][n][3] + bv4.w);
        *(ushort4*)&oh[(size_t)tok * D_M + colb] = h;
      }
    }
  }
  #pragma unroll
  for (int n = 0; n < 4; ++n) {
    int col = bn + wn + n * 16 + l15;
    float bvv = bv[col];
    #pragma unroll
    for (int m = 0; m < 2; ++m) {
      int row0 = bm + wm + m * 16 + kq4;
      ushort4 hv;
      hv.x = f32_bf16_rne(acc[2][m][n][0] + bvv); hv.y = f32_bf16_rne(acc[2][m][n][1] + bvv);
      hv.z = f32_bf16_rne(acc[2][m][n][2] + bvv); hv.w = f32_bf16_rne(acc[2][m][n][3] + bvv);
      size_t idx = (((size_t)(row0 >> 11) * NH + (col >> 6)) * HD + (col & 63)) * SQ + (row0 & 2047);
      *(ushort4*)&vth[idx] = hv;
    }
  }
}

// ------- projection GEMM (Wo), bf16, swapped MFMA, C fp32 -------
__global__ __launch_bounds__(256)
void proj_gemm_k(const unsigned short* __restrict__ Ah_g,
                 const unsigned short* __restrict__ Bh_g,
                 const float* __restrict__ bias, float* __restrict__ C,
                 int M, int N, int K) {
  constexpr int LDK = 40;
  __shared__ unsigned short Ah[64 * LDK];
  __shared__ unsigned short Bh[128 * LDK];
  const int tid = threadIdx.x;
  const int wave = tid >> 6, lane = tid & 63;
  const int wm = (wave >> 1) * 32, wn = (wave & 1) * 64;
  const int bn = blockIdx.x * 128, bm = blockIdx.y * 64;

  f32x4 acc[2][4] = {};
  const int sr = tid >> 2, sk = (tid & 3) * 8;
  const int l15 = lane & 15, k8 = (lane >> 4) * 8;

  for (int k0 = 0; k0 < K; k0 += 32) {
    *(uint4*)&Ah[sr * LDK + sk] = *(const uint4*)&Ah_g[(size_t)(bm + sr) * K + k0 + sk];
    #pragma unroll
    for (int c = 0; c < 2; ++c) {
      int r = sr + c * 64;
      *(uint4*)&Bh[r * LDK + sk] = *(const uint4*)&Bh_g[(size_t)(bn + r) * K + k0 + sk];
    }
    __syncthreads();
    bf16x8 af[2], bfr[4];
    #pragma unroll
    for (int m = 0; m < 2; ++m)
      af[m] = *(bf16x8*)&Ah[(wm + m * 16 + l15) * LDK + k8];
    #pragma unroll
    for (int n = 0; n < 4; ++n)
      bfr[n] = *(bf16x8*)&Bh[(wn + n * 16 + l15) * LDK + k8];
    #pragma unroll
    for (int m = 0; m < 2; ++m)
      #pragma unroll
      for (int n = 0; n < 4; ++n)
        acc[m][n] = __builtin_amdgcn_mfma_f32_16x16x32_bf16(bfr[n], af[m], acc[m][n], 0, 0, 0);
    __syncthreads();
  }
  const int kq4 = (lane >> 4) * 4;
  #pragma unroll
  for (int n = 0; n < 4; ++n) {
    int colb = bn + wn + n * 16 + kq4;
    float4 bv4 = *(const float4*)&bias[colb];
    #pragma unroll
    for (int m = 0; m < 2; ++m) {
      int tok = bm + wm + m * 16 + l15;
      float4 v = {acc[m][n][0] + bv4.x, acc[m][n][1] + bv4.y,
                  acc[m][n][2] + bv4.z, acc[m][n][3] + bv4.w};
      *(float4*)&C[(size_t)tok * N + colb] = v;
    }
  }
}

// ---------------- fused attention v3 (R13-exact): LDS dbuf K/V, q-tile 128, 1 barrier/tile ----------------
__global__ __launch_bounds__(256)
void fused_attn_k(const unsigned short* __restrict__ qh,
                  const unsigned short* __restrict__ kh,
                  const unsigned short* __restrict__ vth,
                  float* __restrict__ attn,
                  unsigned short* __restrict__ ctxh) {
  constexpr int LDK = 72;
  constexpr int NT = SQ / 64;
  __shared__ unsigned short Kth[2][64 * LDK], Vts[2][64 * LDK];
  __shared__ unsigned short Ph[128 * LDK];
  const int tid = threadIdx.x, wave = tid >> 6, lane = tid & 63;
  const int l15 = lane & 15, kq = lane >> 4;
  const int bh = blockIdx.x, b = bh >> 4, h = bh & 15;
  const int q0 = blockIdx.y * 128;

  bf16x8 qfh[2][2];
  #pragma unroll
  for (int qi = 0; qi < 2; ++qi) {
    const size_t qoff = (size_t)(b * SQ + q0 + wave * 32 + qi * 16 + l15) * D_M + h * HD + kq * 8;
    qfh[qi][0] = *(const bf16x8*)&qh[qoff];  qfh[qi][1] = *(const bf16x8*)&qh[qoff + 32];
  }

  const size_t kbase = (size_t)(b * SQ) * D_M + h * HD;
  const size_t vbase = (size_t)bh * HD * SQ;
  const int srow = tid >> 2, sc = (tid & 3) * 16;

  // ---------- pass A ----------
  float lsum[2] = {0.f, 0.f};
  {
    const unsigned short* src = &kh[kbase + (size_t)srow * D_M + sc];
    *(uint4*)&Kth[0][srow * LDK + sc] = *(const uint4*)src;
    *(uint4*)&Kth[0][srow * LDK + sc + 8] = *(const uint4*)(src + 8);
  }
  __syncthreads();
  for (int t = 0; t < NT; ++t) {
    const int cur = t & 1;
    const bool pf = (t + 1 < NT);
    uint4 r0, r1;
    if (pf) {
      const unsigned short* src = &kh[kbase + (size_t)((t + 1) * 64 + srow) * D_M + sc];
      r0 = *(const uint4*)src;
      r1 = *(const uint4*)(src + 8);
    }
    #pragma unroll
    for (int n = 0; n < 4; ++n) {
      bf16x8 kb0 = *(bf16x8*)&Kth[cur][(n * 16 + l15) * LDK + kq * 8];
      bf16x8 kb1 = *(bf16x8*)&Kth[cur][(n * 16 + l15) * LDK + 32 + kq * 8];
      #pragma unroll
      for (int qi = 0; qi < 2; ++qi) {
        f32x4 s = {};
        s = __builtin_amdgcn_mfma_f32_16x16x32_bf16(kb0, qfh[qi][0], s, 0, 0, 0);
        s = __builtin_amdgcn_mfma_f32_16x16x32_bf16(kb1, qfh[qi][1], s, 0, 0, 0);
        #pragma unroll
        for (int r = 0; r < 4; ++r) lsum[qi] += __expf(s[r] * 0.125f);
      }
    }
    if (pf) {
      *(uint4*)&Kth[cur ^ 1][srow * LDK + sc] = r0;
      *(uint4*)&Kth[cur ^ 1][srow * LDK + sc + 8] = r1;
    }
    __syncthreads();
  }
  float invl[2];
  #pragma unroll
  for (int qi = 0; qi < 2; ++qi) {
    float l = lsum[qi];
    l += __shfl_xor(l, 16);
    l += __shfl_xor(l, 32);
    invl[qi] = 1.0f / l;
  }

  // ---------- pass B ----------
  f32x4 cacc[2][4] = {};
  {
    const unsigned short* srch = &kh[kbase + (size_t)srow * D_M + sc];
    const unsigned short* srcv = &vth[vbase + (size_t)srow * SQ + sc];
    *(uint4*)&Kth[0][srow * LDK + sc] = *(const uint4*)srch;
    *(uint4*)&Kth[0][srow * LDK + sc + 8] = *(const uint4*)(srch + 8);
    *(uint4*)&Vts[0][srow * LDK + sc] = *(const uint4*)srcv;
    *(uint4*)&Vts[0][srow * LDK + sc + 8] = *(const uint4*)(srcv + 8);
  }
  __syncthreads();
  for (int t = 0; t < NT; ++t) {
    const int cur = t & 1;
    const int k0 = t * 64;
    const bool pf = (t + 1 < NT);
    uint4 rk0, rk1, rv0, rv1;
    if (pf) {
      const unsigned short* srch = &kh[kbase + (size_t)(k0 + 64 + srow) * D_M + sc];
      const unsigned short* srcv = &vth[vbase + (size_t)srow * SQ + k0 + 64 + sc];
      rk0 = *(const uint4*)srch; rk1 = *(const uint4*)(srch + 8);
      rv0 = *(const uint4*)srcv; rv1 = *(const uint4*)(srcv + 8);
    }
    #pragma unroll
    for (int n = 0; n < 4; ++n) {
      bf16x8 kb0 = *(bf16x8*)&Kth[cur][(n * 16 + l15) * LDK + kq * 8];
      bf16x8 kb1 = *(bf16x8*)&Kth[cur][(n * 16 + l15) * LDK + 32 + kq * 8];
      #pragma unroll
      for (int qi = 0; qi < 2; ++qi) {
        f32x4 s = {};
        s = __builtin_amdgcn_mfma_f32_16x16x32_bf16(kb0, qfh[qi][0], s, 0, 0, 0);
        s = __builtin_amdgcn_mfma_f32_16x16x32_bf16(kb1, qfh[qi][1], s, 0, 0, 0);
        float4 pv;
        pv.x = __expf(s[0] * 0.125f) * invl[qi];
        pv.y = __expf(s[1] * 0.125f) * invl[qi];
        pv.z = __expf(s[2] * 0.125f) * invl[qi];
        pv.w = __expf(s[3] * 0.125f) * invl[qi];
        const int qrow = wave * 32 + qi * 16 + l15;
        *(float4*)&attn[((size_t)bh * SQ + q0 + qrow) * SQ + k0 + n * 16 + kq * 4] = pv;
        ushort4 p4;
        p4.x = f32_bf16_rne(pv.x); p4.y = f32_bf16_rne(pv.y);
        p4.z = f32_bf16_rne(pv.z); p4.w = f32_bf16_rne(pv.w);
        *(ushort4*)&Ph[qrow * LDK + n * 16 + kq * 4] = p4;
      }
    }
    // no barrier: Ph rows are wave-private (validated R12/R13)
    #pragma unroll
    for (int qi = 0; qi < 2; ++qi) {
      bf16x8 pa0 = *(bf16x8*)&Ph[(wave * 32 + qi * 16 + l15) * LDK + kq * 8];
      bf16x8 pa1 = *(bf16x8*)&Ph[(wave * 32 + qi * 16 + l15) * LDK + 32 + kq * 8];
      #pragma unroll
      for (int n = 0; n < 4; ++n) {
        bf16x8 vb0 = *(bf16x8*)&Vts[cur][(n * 16 + l15) * LDK + kq * 8];
        bf16x8 vb1 = *(bf16x8*)&Vts[cur][(n * 16 + l15) * LDK + 32 + kq * 8];
        cacc[qi][n] = __builtin_amdgcn_mfma_f32_16x16x32_bf16(vb0, pa0, cacc[qi][n], 0, 0, 0);
        cacc[qi][n] = __builtin_amdgcn_mfma_f32_16x16x32_bf16(vb1, pa1, cacc[qi][n], 0, 0, 0);
      }
    }
    if (pf) {
      *(uint4*)&Kth[cur ^ 1][srow * LDK + sc] = rk0;
      *(uint4*)&Kth[cur ^ 1][srow * LDK + sc + 8] = rk1;
      *(uint4*)&Vts[cur ^ 1][srow * LDK + sc] = rv0;
      *(uint4*)&Vts[cur ^ 1][srow * LDK + sc + 8] = rv1;
    }
    __syncthreads();
  }
  #pragma unroll
  for (int qi = 0; qi < 2; ++qi)
    #pragma unroll
    for (int n = 0; n < 4; ++n) {
      ushort4 hh;
      hh.x = f32_bf16_rne(cacc[qi][n][0]); hh.y = f32_bf16_rne(cacc[qi][n][1]);
      hh.z = f32_bf16_rne(cacc[qi][n][2]); hh.w = f32_bf16_rne(cacc[qi][n][3]);
      size_t off = (size_t)(b * SQ + q0 + wave * 32 + qi * 16 + l15) * D_M + h * HD + n * 16 + kq * 4;
      *(ushort4*)&ctxh[off] = hh;
    }
}

// ---------------- per-head FF v2: wave-private H (32-token wave tiles), 1 barrier/chunk ----------------
__global__ __launch_bounds__(256)
void ff_bf16_k(const unsigned short* __restrict__ x1h,
               const unsigned short* __restrict__ W1h_, const float* __restrict__ b1,
               const unsigned short* __restrict__ W2h_, const float* __restrict__ b2,
               float* __restrict__ out) {
  constexpr int LDW = 72;
  constexpr int LDH = 40;
  __shared__ unsigned short W1sh[2][32 * LDW];
  __shared__ unsigned short W2sh[2][64 * LDH];
  __shared__ unsigned short Hh[128 * LDH];

  const int tid = threadIdx.x;
  const int wave = tid >> 6, lane = tid & 63;
  const int h = blockIdx.x;
  const int m0 = blockIdx.y * 128;
  const int l15 = lane & 15, kq = lane >> 4;

  const size_t w1base = (size_t)h * FFD * HD;
  const size_t w2base = (size_t)h * HD * FFD;
  const int r1 = tid >> 3, k1 = (tid & 7) * 8;
  const int r2 = tid >> 2, f2 = (tid & 3) * 8;

  // wave owns tokens m0 + wave*32 .. +32 in BOTH phases (H wave-private)
  bf16x8 xf[2][2];
  #pragma unroll
  for (int m = 0; m < 2; ++m)
    #pragma unroll
    for (int ks = 0; ks < 2; ++ks) {
      size_t gof = (size_t)(m0 + wave * 32 + m * 16 + l15) * D_M + h * HD + ks * 32 + kq * 8;
      xf[m][ks] = *(const bf16x8*)&x1h[gof];
    }

  {
    *(uint4*)&W1sh[0][r1 * LDW + k1] = *(const uint4*)&W1h_[w1base + (size_t)r1 * HD + k1];
    *(uint4*)&W2sh[0][r2 * LDH + f2] = *(const uint4*)&W2h_[w2base + (size_t)r2 * FFD + f2];
  }
  __syncthreads();

  f32x4 ffacc[2][4] = {};

  for (int ch = 0; ch < FFD / 32; ++ch) {
    const int buf = ch & 1;
    const bool pf = (ch + 1 < FFD / 32);
    uint4 w1h_r, w2h_r;
    if (pf) {
      const int f0n = (ch + 1) * 32;
      w1h_r = *(const uint4*)&W1h_[w1base + (size_t)(f0n + r1) * HD + k1];
      w2h_r = *(const uint4*)&W2h_[w2base + (size_t)r2 * FFD + f0n + f2];
    }
    // phase 1 (swapped): wave tile 32 tok x 32 f
    f32x4 hacc[2][2] = {};
    #pragma unroll
    for (int ks = 0; ks < 2; ++ks) {
      #pragma unroll
      for (int nf = 0; nf < 2; ++nf) {
        bf16x8 w1f = *(bf16x8*)&W1sh[buf][(nf * 16 + l15) * LDW + ks * 32 + kq * 8];
        #pragma unroll
        for (int m = 0; m < 2; ++m)
          hacc[nf][m] = __builtin_amdgcn_mfma_f32_16x16x32_bf16(w1f, xf[m][ks], hacc[nf][m], 0, 0, 0);
      }
    }
    // bias + relu -> H bf16 (wave-private rows)
    #pragma unroll
    for (int nf = 0; nf < 2; ++nf) {
      const int fb = nf * 16 + kq * 4;
      float4 b1v = *(const float4*)&b1[(size_t)h * FFD + ch * 32 + fb];
      #pragma unroll
      for (int m = 0; m < 2; ++m) {
        int tok = wave * 32 + m * 16 + l15;
        ushort4 hh;
        hh.x = f32_bf16_rne(fmaxf(hacc[nf][m][0] + b1v.x, 0.0f));
        hh.y = f32_bf16_rne(fmaxf(hacc[nf][m][1] + b1v.y, 0.0f));
        hh.z = f32_bf16_rne(fmaxf(hacc[nf][m][2] + b1v.z, 0.0f));
        hh.w = f32_bf16_rne(fmaxf(hacc[nf][m][3] + b1v.w, 0.0f));
        *(ushort4*)&Hh[tok * LDH + fb] = hh;
      }
    }
    // no barrier: H rows wave-private (same-wave LDS ordering)
    bf16x8 hfr[2];
    #pragma unroll
    for (int m = 0; m < 2; ++m)
      hfr[m] = *(bf16x8*)&Hh[(wave * 32 + m * 16 + l15) * LDH + kq * 8];
    // phase 2 (swapped): wave tile 32 tok x 64 d
    #pragma unroll
    for (int n = 0; n < 4; ++n) {
      bf16x8 w2f = *(bf16x8*)&W2sh[buf][(n * 16 + l15) * LDH + kq * 8];
      #pragma unroll
      for (int m = 0; m < 2; ++m)
        ffacc[m][n] = __builtin_amdgcn_mfma_f32_16x16x32_bf16(w2f, hfr[m], ffacc[m][n], 0, 0, 0);
    }
    // write-late: park next W tiles into buf^1 after compute
    if (pf) {
      *(uint4*)&W1sh[buf ^ 1][r1 * LDW + k1] = w1h_r;
      *(uint4*)&W2sh[buf ^ 1][r2 * LDH + f2] = w2h_r;
    }
    __syncthreads();
  }
  // epilogue: vectorized float4 stores
  #pragma unroll
  for (int n = 0; n < 4; ++n) {
    int db = n * 16 + kq * 4;
    float4 b2v = *(const float4*)&b2[(size_t)h * HD + db];
    #pragma unroll
    for (int m = 0; m < 2; ++m) {
      int tok = m0 + wave * 32 + m * 16 + l15;
      float4 v = {ffacc[m][n][0] + b2v.x, ffacc[m][n][1] + b2v.y,
                  ffacc[m][n][2] + b2v.z, ffacc[m][n][3] + b2v.w};
      *(float4*)&out[(size_t)tok * D_M + h * HD + db] = v;
    }
  }
}

// ---------------- out = LayerNorm(a + r) * g + be (optionally + bf16 out) ----------------
template<int BF16OUT>
__global__ __launch_bounds__(256)
void add_ln_kernel(const float* __restrict__ a, const float* __restrict__ r,
                   const float* __restrict__ g, const float* __restrict__ be,
                   float* __restrict__ out, unsigned short* __restrict__ oh) {
  const size_t row = blockIdx.x;
  const int tid = threadIdx.x;
  __shared__ float red1[4];
  __shared__ float red2[4];
  float4 va = ((const float4*)(a + row * D_M))[tid];
  float4 vr = ((const float4*)(r + row * D_M))[tid];
  float v0 = va.x + vr.x, v1 = va.y + vr.y, v2 = va.z + vr.z, v3 = va.w + vr.w;
  float s = v0 + v1 + v2 + v3;
  float sq = v0 * v0 + v1 * v1 + v2 * v2 + v3 * v3;
  s = wave_sum(s);
  sq = wave_sum(sq);
  if ((tid & 63) == 0) { red1[tid >> 6] = s; red2[tid >> 6] = sq; }
  __syncthreads();
  s = red1[0] + red1[1] + red1[2] + red1[3];
  sq = red2[0] + red2[1] + red2[2] + red2[3];
  const float mu = s * (1.0f / D_M);
  const float var = sq * (1.0f / D_M) - mu * mu;
  float x = var + EPS;
  float rs = rsqrtf(x);
  rs = rs * (1.5f - 0.5f * x * rs * rs);
  float4 gg = ((const float4*)g)[tid];
  float4 bb = ((const float4*)be)[tid];
  float4 o = {(v0 - mu) * rs * gg.x + bb.x, (v1 - mu) * rs * gg.y + bb.y,
              (v2 - mu) * rs * gg.z + bb.z, (v3 - mu) * rs * gg.w + bb.w};
  ((float4*)(out + row * D_M))[tid] = o;
  if (BF16OUT) {
    ushort4 h;
    h.x = f32_bf16_rne(o.x); h.y = f32_bf16_rne(o.y);
    h.z = f32_bf16_rne(o.z); h.w = f32_bf16_rne(o.w);
    ((ushort4*)(oh + row * D_M))[tid] = h;
  }
}

extern "C" void kernel_launch(void* const* d_in, const int* in_sizes, int n_in,
                              void* d_out, int out_size, void* d_ws, size_t ws_size,
                              hipStream_t stream) {
  const float* x   = (const float*)d_in[0];
  const float* Wq  = (const float*)d_in[1];
  const float* bq  = (const float*)d_in[2];
  const float* Wk  = (const float*)d_in[3];
  const float* bk  = (const float*)d_in[4];
  const float* Wv  = (const float*)d_in[5];
  const float* bv  = (const float*)d_in[6];
  const float* Wo  = (const float*)d_in[7];
  const float* bo  = (const float*)d_in[8];
  const float* W1  = (const float*)d_in[9];
  const float* b1  = (const float*)d_in[10];
  const float* W2  = (const float*)d_in[11];
  const float* b2  = (const float*)d_in[12];
  const float* g1  = (const float*)d_in[13];
  const float* be1 = (const float*)d_in[14];
  const float* g2  = (const float*)d_in[15];
  const float* be2 = (const float*)d_in[16];

  float* y_out = (float*)d_out;
  float* attn  = (float*)d_out + (size_t)TOK * D_M;

  // ---- workspace: 80 MB ----
  char* p = (char*)d_ws;
  const size_t MB = 1024 * 1024;
  unsigned short* WqT = (unsigned short*)(p + 0 * MB);    // 2 MB each
  unsigned short* WkT = (unsigned short*)(p + 2 * MB);
  unsigned short* WvT = (unsigned short*)(p + 4 * MB);
  unsigned short* WoT = (unsigned short*)(p + 6 * MB);
  unsigned short* xh  = (unsigned short*)(p + 8 * MB);    // 8 MB
  unsigned short* qh  = (unsigned short*)(p + 16 * MB);   // 8 MB
  unsigned short* kh  = (unsigned short*)(p + 24 * MB);   // 8 MB
  unsigned short* vth = (unsigned short*)(p + 32 * MB);   // 8 MB
  unsigned short* ctxh = (unsigned short*)(p + 40 * MB);  // 8 MB
  float* resid = (float*)(p + 48 * MB);                   // 16 MB
  float* x1b   = (float*)(p + 64 * MB);                   // 16 MB
  // phase aliases (after attention / Wo):
  unsigned short* x1c_h = (unsigned short*)(p + 8 * MB);  // xh dead after QKV
  unsigned short* W1c_h = (unsigned short*)(p + 16 * MB); // qh dead after attn
  unsigned short* W2c_h = (unsigned short*)(p + 24 * MB); // kh dead after attn
  float* ffb = (float*)(p + 32 * MB);                     // vth+ctxh dead after Wo gemm (16 MB)

  const dim3 blk(256);
  const int n4_act = TOK * D_M / 4;   // 1,048,576

  // ---- prep: 4 weight transposes (bf16) + x convert ----
  transp4_k<<<dim3(16, 16, 4), blk, 0, stream>>>(Wq, Wk, Wv, Wo, WqT, WkT, WvT, WoT);
  convert_bf16_k<<<dim3(n4_act / 256), blk, 0, stream>>>(x, xh, n4_act);

  // ---- merged QKV projection (bf16), panel-pinned grid ----
  qkv_gemm_k<<<dim3(D_M / 128, TOK / 64), blk, 0, stream>>>(
      xh, WqT, WkT, WvT, bq, bk, bv, qh, kh, vth);

  // ---- fused attention v3 (R13-exact) ----
  fused_attn_k<<<dim3(BB * NH, SQ / 128), blk, 0, stream>>>(qh, kh, vth, attn, ctxh);

  // ---- Wo projection + LN1 (LN1 emits bf16 x1) ----
  proj_gemm_k<<<dim3(D_M / 128, TOK / 64), blk, 0, stream>>>(
      ctxh, WoT, bo, resid, TOK, D_M, D_M);
  add_ln_kernel<1><<<dim3(TOK), blk, 0, stream>>>(x, resid, g1, be1, x1b, x1c_h);

  // ---- per-head FF v2 (wave-private H) + LN2 ----
  convert2_bf16_k<<<dim3(n4_act / 256, 2), blk, 0, stream>>>(W1, W1c_h, W2, W2c_h, n4_act);
  ff_bf16_k<<<dim3(NH, TOK / 128), blk, 0, stream>>>(x1c_h, W1c_h, b1, W2c_h, b2, ffb);
  add_ln_kernel<0><<<dim3(TOK), blk, 0, stream>>>(x1b, ffb, g2, be2, y_out, nullptr);
}

// Round 16
// 472.993 us; speedup vs baseline: 1.1034x; 1.1034x over previous
//
#include <hip/hip_runtime.h>
#include <cstddef>

#define D_M 1024
#define NH 16
#define HD 64
#define FFD 4096
#define SQ 2048
#define BB 2
#define TOK (BB*SQ)   // 4096
#define EPS 1e-5f

typedef __attribute__((ext_vector_type(8))) short bf16x8;
typedef __attribute__((ext_vector_type(4))) float f32x4;

__device__ inline unsigned short f32_bf16_rne(float f) {
  unsigned int u = __float_as_uint(f);
  unsigned int r = (u + 0x7fffu + ((u >> 16) & 1u)) >> 16;
  return (unsigned short)r;
}

__device__ inline float wave_sum(float v) {
  #pragma unroll
  for (int m = 32; m >= 1; m >>= 1) v += __shfl_xor(v, m);
  return v;
}

// ---------------- fp32 -> bf16 (RNE), vectorized ----------------
__global__ __launch_bounds__(256)
void convert_bf16_k(const float* __restrict__ src, unsigned short* __restrict__ dst, int n4) {
  int i = blockIdx.x * 256 + threadIdx.x;
  if (i >= n4) return;
  float4 v = ((const float4*)src)[i];
  ushort4 h;
  h.x = f32_bf16_rne(v.x); h.y = f32_bf16_rne(v.y);
  h.z = f32_bf16_rne(v.z); h.w = f32_bf16_rne(v.w);
  ((ushort4*)dst)[i] = h;
}

// ---------------- fp32 -> bf16, 2 tensors in one launch ----------------
__global__ __launch_bounds__(256)
void convert2_bf16_k(const float* __restrict__ s0, unsigned short* __restrict__ d0,
                     const float* __restrict__ s1, unsigned short* __restrict__ d1, int n4) {
  const float* src = blockIdx.y ? s1 : s0;
  unsigned short* dst = blockIdx.y ? d1 : d0;
  int i = blockIdx.x * 256 + threadIdx.x;
  if (i >= n4) return;
  float4 v = ((const float4*)src)[i];
  ushort4 h;
  h.x = f32_bf16_rne(v.x); h.y = f32_bf16_rne(v.y);
  h.z = f32_bf16_rne(v.z); h.w = f32_bf16_rne(v.w);
  ((ushort4*)dst)[i] = h;
}

// ---------------- 4x W[1024][1024] fp32 -> WT bf16 [N][K], one launch ----------------
__global__ __launch_bounds__(256)
void transp4_k(const float* __restrict__ W0, const float* __restrict__ W1_,
               const float* __restrict__ W2_, const float* __restrict__ W3,
               unsigned short* __restrict__ h0, unsigned short* __restrict__ h1,
               unsigned short* __restrict__ h2, unsigned short* __restrict__ h3) {
  const float* W; unsigned short* hT;
  switch (blockIdx.z) {
    case 0: W = W0; hT = h0; break;
    case 1: W = W1_; hT = h1; break;
    case 2: W = W2_; hT = h2; break;
    default: W = W3; hT = h3; break;
  }
  __shared__ float tile[64][65];
  const int bn = blockIdx.x * 64;
  const int bk = blockIdx.y * 64;
  const int t = threadIdx.x;
  #pragma unroll
  for (int i = 0; i < 4; ++i) {
    int r = (t >> 4) + i * 16, c = (t & 15) * 4;
    float4 v = *(const float4*)&W[(size_t)(bk + r) * D_M + bn + c];
    tile[r][c] = v.x; tile[r][c + 1] = v.y; tile[r][c + 2] = v.z; tile[r][c + 3] = v.w;
  }
  __syncthreads();
  #pragma unroll
  for (int i = 0; i < 4; ++i) {
    int n = (t >> 4) + i * 16, k = (t & 15) * 4;
    ushort4 h;
    h.x = f32_bf16_rne(tile[k][n]);     h.y = f32_bf16_rne(tile[k + 1][n]);
    h.z = f32_bf16_rne(tile[k + 2][n]); h.w = f32_bf16_rne(tile[k + 3][n]);
    *(ushort4*)&hT[(size_t)(bn + n) * D_M + bk + k] = h;
  }
}

// ---------------- merged QKV GEMM, bf16, one A-tile for 3 weight sets ----------------
__global__ __launch_bounds__(256)
void qkv_gemm_k(const unsigned short* __restrict__ xh_g,
                const unsigned short* __restrict__ Bqh, const unsigned short* __restrict__ Bkh,
                const unsigned short* __restrict__ Bvh,
                const float* __restrict__ bq, const float* __restrict__ bk, const float* __restrict__ bv,
                unsigned short* __restrict__ qh, unsigned short* __restrict__ kh,
                unsigned short* __restrict__ vth) {
  constexpr int LDK = 40;
  __shared__ unsigned short Ah[64 * LDK];
  __shared__ unsigned short Bh[3][128 * LDK];
  const int tid = threadIdx.x;
  const int wave = tid >> 6, lane = tid & 63;
  const int wm = (wave >> 1) * 32, wn = (wave & 1) * 64;
  const int bn = blockIdx.x * 128, bm = blockIdx.y * 64;
  const int K = D_M;

  f32x4 acc[3][2][4] = {};
  const int sr = tid >> 2, sk = (tid & 3) * 8;
  const int l15 = lane & 15, k8 = (lane >> 4) * 8;

  const unsigned short* Bhp[3] = {Bqh, Bkh, Bvh};

  for (int k0 = 0; k0 < K; k0 += 32) {
    *(uint4*)&Ah[sr * LDK + sk] = *(const uint4*)&xh_g[(size_t)(bm + sr) * K + k0 + sk];
    #pragma unroll
    for (int s = 0; s < 3; ++s) {
      #pragma unroll
      for (int c = 0; c < 2; ++c) {
        int r = sr + c * 64;
        *(uint4*)&Bh[s][r * LDK + sk] = *(const uint4*)&Bhp[s][(size_t)(bn + r) * K + k0 + sk];
      }
    }
    __syncthreads();
    bf16x8 af[2];
    #pragma unroll
    for (int m = 0; m < 2; ++m)
      af[m] = *(bf16x8*)&Ah[(wm + m * 16 + l15) * LDK + k8];
    #pragma unroll
    for (int s = 0; s < 3; ++s) {
      #pragma unroll
      for (int n = 0; n < 4; ++n) {
        bf16x8 b0 = *(bf16x8*)&Bh[s][(wn + n * 16 + l15) * LDK + k8];
        #pragma unroll
        for (int m = 0; m < 2; ++m) {
          if (s == 2) {
            acc[s][m][n] = __builtin_amdgcn_mfma_f32_16x16x32_bf16(af[m], b0, acc[s][m][n], 0, 0, 0);
          } else {
            acc[s][m][n] = __builtin_amdgcn_mfma_f32_16x16x32_bf16(b0, af[m], acc[s][m][n], 0, 0, 0);
          }
        }
      }
    }
    __syncthreads();
  }
  const int kq4 = (lane >> 4) * 4;
  #pragma unroll
  for (int s = 0; s < 2; ++s) {
    const float* bias = (s == 0) ? bq : bk;
    unsigned short* oh = (s == 0) ? qh : kh;
    #pragma unroll
    for (int n = 0; n < 4; ++n) {
      int colb = bn + wn + n * 16 + kq4;
      float4 bv4 = *(const float4*)&bias[colb];
      #pragma unroll
      for (int m = 0; m < 2; ++m) {
        int tok = bm + wm + m * 16 + l15;
        ushort4 h;
        h.x = f32_bf16_rne(acc[s][m][n][0] + bv4.x);
        h.y = f32_bf16_rne(acc[s][m][n][1] + bv4.y);
        h.z = f32_bf16_rne(acc[s][m][n][2] + bv4.z);
        h.w = f32_bf16_rne(acc[s][m][n][3] + bv4.w);
        *(ushort4*)&oh[(size_t)tok * D_M + colb] = h;
      }
    }
  }
  #pragma unroll
  for (int n = 0; n < 4; ++n) {
    int col = bn + wn + n * 16 + l15;
    float bvv = bv[col];
    #pragma unroll
    for (int m = 0; m < 2; ++m) {
      int row0 = bm + wm + m * 16 + kq4;
      ushort4 hv;
      hv.x = f32_bf16_rne(acc[2][m][n][0] + bvv); hv.y = f32_bf16_rne(acc[2][m][n][1] + bvv);
      hv.z = f32_bf16_rne(acc[2][m][n][2] + bvv); hv.w = f32_bf16_rne(acc[2][m][n][3] + bvv);
      size_t idx = (((size_t)(row0 >> 11) * NH + (col >> 6)) * HD + (col & 63)) * SQ + (row0 & 2047);
      *(ushort4*)&vth[idx] = hv;
    }
  }
}

// ------- projection GEMM (Wo), bf16, swapped MFMA, C fp32 -------
__global__ __launch_bounds__(256)
void proj_gemm_k(const unsigned short* __restrict__ Ah_g,
                 const unsigned short* __restrict__ Bh_g,
                 const float* __restrict__ bias, float* __restrict__ C,
                 int M, int N, int K) {
  constexpr int LDK = 40;
  __shared__ unsigned short Ah[64 * LDK];
  __shared__ unsigned short Bh[128 * LDK];
  const int tid = threadIdx.x;
  const int wave = tid >> 6, lane = tid & 63;
  const int wm = (wave >> 1) * 32, wn = (wave & 1) * 64;
  const int bn = blockIdx.x * 128, bm = blockIdx.y * 64;

  f32x4 acc[2][4] = {};
  const int sr = tid >> 2, sk = (tid & 3) * 8;
  const int l15 = lane & 15, k8 = (lane >> 4) * 8;

  for (int k0 = 0; k0 < K; k0 += 32) {
    *(uint4*)&Ah[sr * LDK + sk] = *(const uint4*)&Ah_g[(size_t)(bm + sr) * K + k0 + sk];
    #pragma unroll
    for (int c = 0; c < 2; ++c) {
      int r = sr + c * 64;
      *(uint4*)&Bh[r * LDK + sk] = *(const uint4*)&Bh_g[(size_t)(bn + r) * K + k0 + sk];
    }
    __syncthreads();
    bf16x8 af[2], bfr[4];
    #pragma unroll
    for (int m = 0; m < 2; ++m)
      af[m] = *(bf16x8*)&Ah[(wm + m * 16 + l15) * LDK + k8];
    #pragma unroll
    for (int n = 0; n < 4; ++n)
      bfr[n] = *(bf16x8*)&Bh[(wn + n * 16 + l15) * LDK + k8];
    #pragma unroll
    for (int m = 0; m < 2; ++m)
      #pragma unroll
      for (int n = 0; n < 4; ++n)
        acc[m][n] = __builtin_amdgcn_mfma_f32_16x16x32_bf16(bfr[n], af[m], acc[m][n], 0, 0, 0);
    __syncthreads();
  }
  const int kq4 = (lane >> 4) * 4;
  #pragma unroll
  for (int n = 0; n < 4; ++n) {
    int colb = bn + wn + n * 16 + kq4;
    float4 bv4 = *(const float4*)&bias[colb];
    #pragma unroll
    for (int m = 0; m < 2; ++m) {
      int tok = bm + wm + m * 16 + l15;
      float4 v = {acc[m][n][0] + bv4.x, acc[m][n][1] + bv4.y,
                  acc[m][n][2] + bv4.z, acc[m][n][3] + bv4.w};
      *(float4*)&C[(size_t)tok * N + colb] = v;
    }
  }
}

// ---------------- fused attention v4 (R14): pass A 128-row dbuf; pass B 64-row dbuf ----------------
// grid: (bh, q-tile). Ph rows wave-private (no mid barrier).
__global__ __launch_bounds__(256)
void fused_attn_k(const unsigned short* __restrict__ qh,
                  const unsigned short* __restrict__ kh,
                  const unsigned short* __restrict__ vth,
                  float* __restrict__ attn,
                  unsigned short* __restrict__ ctxh) {
  constexpr int LDK = 72;
  __shared__ unsigned short arena[6 * 64 * LDK];   // 27648 shorts = 55.3 KB
  const int tid = threadIdx.x, wave = tid >> 6, lane = tid & 63;
  const int l15 = lane & 15, kq = lane >> 4;
  const int bh = blockIdx.x, b = bh >> 4, h = bh & 15;
  const int q0 = blockIdx.y * 128;

  bf16x8 qfh[2][2];
  #pragma unroll
  for (int qi = 0; qi < 2; ++qi) {
    const size_t qoff = (size_t)(b * SQ + q0 + wave * 32 + qi * 16 + l15) * D_M + h * HD + kq * 8;
    qfh[qi][0] = *(const bf16x8*)&qh[qoff];  qfh[qi][1] = *(const bf16x8*)&qh[qoff + 32];
  }

  const size_t kbase = (size_t)(b * SQ) * D_M + h * HD;
  const size_t vbase = (size_t)bh * HD * SQ;
  const int srow = tid >> 2, sc = (tid & 3) * 16;

  // ---------- pass A: 128-row K tiles, dbuf ----------
  float lsum[2] = {0.f, 0.f};
  {
    #pragma unroll
    for (int hlf = 0; hlf < 2; ++hlf) {
      const int row = srow + hlf * 64;
      const unsigned short* src = &kh[kbase + (size_t)row * D_M + sc];
      *(uint4*)&arena[row * LDK + sc] = *(const uint4*)src;
      *(uint4*)&arena[row * LDK + sc + 8] = *(const uint4*)(src + 8);
    }
  }
  __syncthreads();
  for (int t = 0; t < SQ / 128; ++t) {
    const int abuf = (t & 1) * 9216;
    const bool pf = (t + 1 < SQ / 128);
    uint4 r0[2], r1[2];
    if (pf) {
      #pragma unroll
      for (int hlf = 0; hlf < 2; ++hlf) {
        const unsigned short* src = &kh[kbase + (size_t)((t + 1) * 128 + srow + hlf * 64) * D_M + sc];
        r0[hlf] = *(const uint4*)src;
        r1[hlf] = *(const uint4*)(src + 8);
      }
    }
    #pragma unroll
    for (int n = 0; n < 8; ++n) {
      bf16x8 kb0 = *(bf16x8*)&arena[abuf + (n * 16 + l15) * LDK + kq * 8];
      bf16x8 kb1 = *(bf16x8*)&arena[abuf + (n * 16 + l15) * LDK + 32 + kq * 8];
      #pragma unroll
      for (int qi = 0; qi < 2; ++qi) {
        f32x4 s = {};
        s = __builtin_amdgcn_mfma_f32_16x16x32_bf16(kb0, qfh[qi][0], s, 0, 0, 0);
        s = __builtin_amdgcn_mfma_f32_16x16x32_bf16(kb1, qfh[qi][1], s, 0, 0, 0);
        #pragma unroll
        for (int r = 0; r < 4; ++r) lsum[qi] += __expf(s[r] * 0.125f);
      }
    }
    if (pf) {
      const int nbuf = ((t + 1) & 1) * 9216;
      #pragma unroll
      for (int hlf = 0; hlf < 2; ++hlf) {
        const int row = srow + hlf * 64;
        *(uint4*)&arena[nbuf + row * LDK + sc] = r0[hlf];
        *(uint4*)&arena[nbuf + row * LDK + sc + 8] = r1[hlf];
      }
    }
    __syncthreads();
  }
  float invl[2];
  #pragma unroll
  for (int qi = 0; qi < 2; ++qi) {
    float l = lsum[qi];
    l += __shfl_xor(l, 16);
    l += __shfl_xor(l, 32);
    invl[qi] = 1.0f / l;
  }

  // ---------- pass B: 64-row K+V dbuf, Ph wave-private, 1 barrier/tile ----------
  unsigned short* Ph = arena + 18432;
  f32x4 cacc[2][4] = {};
  {
    const unsigned short* srch = &kh[kbase + (size_t)srow * D_M + sc];
    const unsigned short* srcv = &vth[vbase + (size_t)srow * SQ + sc];
    *(uint4*)&arena[srow * LDK + sc] = *(const uint4*)srch;
    *(uint4*)&arena[srow * LDK + sc + 8] = *(const uint4*)(srch + 8);
    *(uint4*)&arena[9216 + srow * LDK + sc] = *(const uint4*)srcv;
    *(uint4*)&arena[9216 + srow * LDK + sc + 8] = *(const uint4*)(srcv + 8);
  }
  __syncthreads();
  for (int t = 0; t < SQ / 64; ++t) {
    const int kbuf = (t & 1) * 4608;
    const int vbuf = 9216 + (t & 1) * 4608;
    const int k0 = t * 64;
    const bool pf = (t + 1 < SQ / 64);
    uint4 rk0, rk1, rv0, rv1;
    if (pf) {
      const unsigned short* srch = &kh[kbase + (size_t)(k0 + 64 + srow) * D_M + sc];
      const unsigned short* srcv = &vth[vbase + (size_t)srow * SQ + k0 + 64 + sc];
      rk0 = *(const uint4*)srch; rk1 = *(const uint4*)(srch + 8);
      rv0 = *(const uint4*)srcv; rv1 = *(const uint4*)(srcv + 8);
    }
    #pragma unroll
    for (int n = 0; n < 4; ++n) {
      bf16x8 kb0 = *(bf16x8*)&arena[kbuf + (n * 16 + l15) * LDK + kq * 8];
      bf16x8 kb1 = *(bf16x8*)&arena[kbuf + (n * 16 + l15) * LDK + 32 + kq * 8];
      #pragma unroll
      for (int qi = 0; qi < 2; ++qi) {
        f32x4 s = {};
        s = __builtin_amdgcn_mfma_f32_16x16x32_bf16(kb0, qfh[qi][0], s, 0, 0, 0);
        s = __builtin_amdgcn_mfma_f32_16x16x32_bf16(kb1, qfh[qi][1], s, 0, 0, 0);
        float4 pv;
        pv.x = __expf(s[0] * 0.125f) * invl[qi];
        pv.y = __expf(s[1] * 0.125f) * invl[qi];
        pv.z = __expf(s[2] * 0.125f) * invl[qi];
        pv.w = __expf(s[3] * 0.125f) * invl[qi];
        const int qrow = wave * 32 + qi * 16 + l15;
        *(float4*)&attn[((size_t)bh * SQ + q0 + qrow) * SQ + k0 + n * 16 + kq * 4] = pv;
        ushort4 p4;
        p4.x = f32_bf16_rne(pv.x); p4.y = f32_bf16_rne(pv.y);
        p4.z = f32_bf16_rne(pv.z); p4.w = f32_bf16_rne(pv.w);
        *(ushort4*)&Ph[qrow * LDK + n * 16 + kq * 4] = p4;
      }
    }
    // no barrier: Ph rows are wave-private
    #pragma unroll
    for (int qi = 0; qi < 2; ++qi) {
      bf16x8 pa0 = *(bf16x8*)&Ph[(wave * 32 + qi * 16 + l15) * LDK + kq * 8];
      bf16x8 pa1 = *(bf16x8*)&Ph[(wave * 32 + qi * 16 + l15) * LDK + 32 + kq * 8];
      #pragma unroll
      for (int n = 0; n < 4; ++n) {
        bf16x8 vb0 = *(bf16x8*)&arena[vbuf + (n * 16 + l15) * LDK + kq * 8];
        bf16x8 vb1 = *(bf16x8*)&arena[vbuf + (n * 16 + l15) * LDK + 32 + kq * 8];
        cacc[qi][n] = __builtin_amdgcn_mfma_f32_16x16x32_bf16(vb0, pa0, cacc[qi][n], 0, 0, 0);
        cacc[qi][n] = __builtin_amdgcn_mfma_f32_16x16x32_bf16(vb1, pa1, cacc[qi][n], 0, 0, 0);
      }
    }
    if (pf) {
      const int nk = ((t + 1) & 1) * 4608;
      const int nv = 9216 + ((t + 1) & 1) * 4608;
      *(uint4*)&arena[nk + srow * LDK + sc] = rk0;
      *(uint4*)&arena[nk + srow * LDK + sc + 8] = rk1;
      *(uint4*)&arena[nv + srow * LDK + sc] = rv0;
      *(uint4*)&arena[nv + srow * LDK + sc + 8] = rv1;
    }
    __syncthreads();
  }
  #pragma unroll
  for (int qi = 0; qi < 2; ++qi)
    #pragma unroll
    for (int n = 0; n < 4; ++n) {
      ushort4 hh;
      hh.x = f32_bf16_rne(cacc[qi][n][0]); hh.y = f32_bf16_rne(cacc[qi][n][1]);
      hh.z = f32_bf16_rne(cacc[qi][n][2]); hh.w = f32_bf16_rne(cacc[qi][n][3]);
      size_t off = (size_t)(b * SQ + q0 + wave * 32 + qi * 16 + l15) * D_M + h * HD + n * 16 + kq * 4;
      *(ushort4*)&ctxh[off] = hh;
    }
}

// ---------------- per-head FF v1 (R13): 4-subtile waves, 2 barriers/chunk, reg-staged W ----------------
__global__ __launch_bounds__(256)
void ff_bf16_k(const unsigned short* __restrict__ x1h,
               const unsigned short* __restrict__ W1h_, const float* __restrict__ b1,
               const unsigned short* __restrict__ W2h_, const float* __restrict__ b2,
               float* __restrict__ out) {
  constexpr int LDW = 72;
  constexpr int LDH = 40;
  __shared__ unsigned short W1sh[2][32 * LDW];
  __shared__ unsigned short W2sh[2][64 * LDH];
  __shared__ unsigned short Hh[128 * LDH];

  const int tid = threadIdx.x;
  const int wave = tid >> 6, lane = tid & 63;
  const int wm = wave >> 1, wf = wave & 1, wd = wave & 1;
  const int h = blockIdx.x;
  const int m0 = blockIdx.y * 128;
  const int l15 = lane & 15, kq = lane >> 4;

  const size_t w1base = (size_t)h * FFD * HD;
  const size_t w2base = (size_t)h * HD * FFD;
  const int r1 = tid >> 3, k1 = (tid & 7) * 8;
  const int r2 = tid >> 2, f2 = (tid & 3) * 8;

  bf16x8 xf[4][2];
  #pragma unroll
  for (int m = 0; m < 4; ++m)
    #pragma unroll
    for (int ks = 0; ks < 2; ++ks) {
      size_t gof = (size_t)(m0 + wm * 64 + m * 16 + l15) * D_M + h * HD + ks * 32 + kq * 8;
      xf[m][ks] = *(const bf16x8*)&x1h[gof];
    }

  {
    *(uint4*)&W1sh[0][r1 * LDW + k1] = *(const uint4*)&W1h_[w1base + (size_t)r1 * HD + k1];
    *(uint4*)&W2sh[0][r2 * LDH + f2] = *(const uint4*)&W2h_[w2base + (size_t)r2 * FFD + f2];
  }
  __syncthreads();

  f32x4 ffacc[4][2] = {};

  for (int ch = 0; ch < FFD / 32; ++ch) {
    const int buf = ch & 1;
    const bool pf = (ch + 1 < FFD / 32);
    uint4 w1h_r, w2h_r;
    if (pf) {
      const int f0n = (ch + 1) * 32;
      w1h_r = *(const uint4*)&W1h_[w1base + (size_t)(f0n + r1) * HD + k1];
      w2h_r = *(const uint4*)&W2h_[w2base + (size_t)r2 * FFD + f0n + f2];
    }
    // phase 1 (swapped): hacc[m] col = token (l15), rows = f (kq*4+r)
    f32x4 hacc[4] = {};
    #pragma unroll
    for (int ks = 0; ks < 2; ++ks) {
      bf16x8 w1h = *(bf16x8*)&W1sh[buf][(wf * 16 + l15) * LDW + ks * 32 + kq * 8];
      #pragma unroll
      for (int m = 0; m < 4; ++m)
        hacc[m] = __builtin_amdgcn_mfma_f32_16x16x32_bf16(w1h, xf[m][ks], hacc[m], 0, 0, 0);
    }
    // bias + relu -> H bf16 (vectorized)
    {
      const int fb = wf * 16 + kq * 4;
      float4 b1v = *(const float4*)&b1[(size_t)h * FFD + ch * 32 + fb];
      const float bb[4] = {b1v.x, b1v.y, b1v.z, b1v.w};
      #pragma unroll
      for (int m = 0; m < 4; ++m) {
        int tok = wm * 64 + m * 16 + l15;
        ushort4 hh;
        hh.x = f32_bf16_rne(fmaxf(hacc[m][0] + bb[0], 0.0f));
        hh.y = f32_bf16_rne(fmaxf(hacc[m][1] + bb[1], 0.0f));
        hh.z = f32_bf16_rne(fmaxf(hacc[m][2] + bb[2], 0.0f));
        hh.w = f32_bf16_rne(fmaxf(hacc[m][3] + bb[3], 0.0f));
        *(ushort4*)&Hh[tok * LDH + fb] = hh;
      }
    }
    __syncthreads();
    bf16x8 hfr[4];
    #pragma unroll
    for (int m = 0; m < 4; ++m)
      hfr[m] = *(bf16x8*)&Hh[(wm * 64 + m * 16 + l15) * LDH + kq * 8];
    // phase 2 (swapped): ffacc col = token, rows = d
    #pragma unroll
    for (int n = 0; n < 2; ++n) {
      bf16x8 w2h = *(bf16x8*)&W2sh[buf][(wd * 32 + n * 16 + l15) * LDH + kq * 8];
      #pragma unroll
      for (int m = 0; m < 4; ++m)
        ffacc[m][n] = __builtin_amdgcn_mfma_f32_16x16x32_bf16(w2h, hfr[m], ffacc[m][n], 0, 0, 0);
    }
    // write-late: park next W tiles into buf^1 after compute
    if (pf) {
      *(uint4*)&W1sh[buf ^ 1][r1 * LDW + k1] = w1h_r;
      *(uint4*)&W2sh[buf ^ 1][r2 * LDH + f2] = w2h_r;
    }
    __syncthreads();
  }
  // epilogue: vectorized float4 stores
  #pragma unroll
  for (int n = 0; n < 2; ++n) {
    int db = wd * 32 + n * 16 + kq * 4;
    float4 b2v = *(const float4*)&b2[(size_t)h * HD + db];
    #pragma unroll
    for (int m = 0; m < 4; ++m) {
      int tok = m0 + wm * 64 + m * 16 + l15;
      float4 v = {ffacc[m][n][0] + b2v.x, ffacc[m][n][1] + b2v.y,
                  ffacc[m][n][2] + b2v.z, ffacc[m][n][3] + b2v.w};
      *(float4*)&out[(size_t)tok * D_M + h * HD + db] = v;
    }
  }
}

// ---------------- out = LayerNorm(a + r) * g + be (optionally + bf16 out) ----------------
template<int BF16OUT>
__global__ __launch_bounds__(256)
void add_ln_kernel(const float* __restrict__ a, const float* __restrict__ r,
                   const float* __restrict__ g, const float* __restrict__ be,
                   float* __restrict__ out, unsigned short* __restrict__ oh) {
  const size_t row = blockIdx.x;
  const int tid = threadIdx.x;
  __shared__ float red1[4];
  __shared__ float red2[4];
  float4 va = ((const float4*)(a + row * D_M))[tid];
  float4 vr = ((const float4*)(r + row * D_M))[tid];
  float v0 = va.x + vr.x, v1 = va.y + vr.y, v2 = va.z + vr.z, v3 = va.w + vr.w;
  float s = v0 + v1 + v2 + v3;
  float sq = v0 * v0 + v1 * v1 + v2 * v2 + v3 * v3;
  s = wave_sum(s);
  sq = wave_sum(sq);
  if ((tid & 63) == 0) { red1[tid >> 6] = s; red2[tid >> 6] = sq; }
  __syncthreads();
  s = red1[0] + red1[1] + red1[2] + red1[3];
  sq = red2[0] + red2[1] + red2[2] + red2[3];
  const float mu = s * (1.0f / D_M);
  const float var = sq * (1.0f / D_M) - mu * mu;
  float x = var + EPS;
  float rs = rsqrtf(x);
  rs = rs * (1.5f - 0.5f * x * rs * rs);
  float4 gg = ((const float4*)g)[tid];
  float4 bb = ((const float4*)be)[tid];
  float4 o = {(v0 - mu) * rs * gg.x + bb.x, (v1 - mu) * rs * gg.y + bb.y,
              (v2 - mu) * rs * gg.z + bb.z, (v3 - mu) * rs * gg.w + bb.w};
  ((float4*)(out + row * D_M))[tid] = o;
  if (BF16OUT) {
    ushort4 h;
    h.x = f32_bf16_rne(o.x); h.y = f32_bf16_rne(o.y);
    h.z = f32_bf16_rne(o.z); h.w = f32_bf16_rne(o.w);
    ((ushort4*)(oh + row * D_M))[tid] = h;
  }
}

extern "C" void kernel_launch(void* const* d_in, const int* in_sizes, int n_in,
                              void* d_out, int out_size, void* d_ws, size_t ws_size,
                              hipStream_t stream) {
  const float* x   = (const float*)d_in[0];
  const float* Wq  = (const float*)d_in[1];
  const float* bq  = (const float*)d_in[2];
  const float* Wk  = (const float*)d_in[3];
  const float* bk  = (const float*)d_in[4];
  const float* Wv  = (const float*)d_in[5];
  const float* bv  = (const float*)d_in[6];
  const float* Wo  = (const float*)d_in[7];
  const float* bo  = (const float*)d_in[8];
  const float* W1  = (const float*)d_in[9];
  const float* b1  = (const float*)d_in[10];
  const float* W2  = (const float*)d_in[11];
  const float* b2  = (const float*)d_in[12];
  const float* g1  = (const float*)d_in[13];
  const float* be1 = (const float*)d_in[14];
  const float* g2  = (const float*)d_in[15];
  const float* be2 = (const float*)d_in[16];

  float* y_out = (float*)d_out;
  float* attn  = (float*)d_out + (size_t)TOK * D_M;

  // ---- workspace: 80 MB ----
  char* p = (char*)d_ws;
  const size_t MB = 1024 * 1024;
  unsigned short* WqT = (unsigned short*)(p + 0 * MB);
  unsigned short* WkT = (unsigned short*)(p + 2 * MB);
  unsigned short* WvT = (unsigned short*)(p + 4 * MB);
  unsigned short* WoT = (unsigned short*)(p + 6 * MB);
  unsigned short* xh  = (unsigned short*)(p + 8 * MB);
  unsigned short* qh  = (unsigned short*)(p + 16 * MB);
  unsigned short* kh  = (unsigned short*)(p + 24 * MB);
  unsigned short* vth = (unsigned short*)(p + 32 * MB);
  unsigned short* ctxh = (unsigned short*)(p + 40 * MB);
  float* resid = (float*)(p + 48 * MB);
  float* x1b   = (float*)(p + 64 * MB);
  // phase aliases:
  unsigned short* x1c_h = (unsigned short*)(p + 8 * MB);  // xh dead after QKV
  unsigned short* W1c_h = (unsigned short*)(p + 16 * MB); // qh dead after attn
  unsigned short* W2c_h = (unsigned short*)(p + 24 * MB); // kh dead after attn
  float* ffb = (float*)(p + 32 * MB);                     // vth+ctxh dead after Wo gemm

  const dim3 blk(256);
  const int n4_act = TOK * D_M / 4;

  transp4_k<<<dim3(16, 16, 4), blk, 0, stream>>>(Wq, Wk, Wv, Wo, WqT, WkT, WvT, WoT);
  convert_bf16_k<<<dim3(n4_act / 256), blk, 0, stream>>>(x, xh, n4_act);

  qkv_gemm_k<<<dim3(D_M / 128, TOK / 64), blk, 0, stream>>>(
      xh, WqT, WkT, WvT, bq, bk, bv, qh, kh, vth);

  fused_attn_k<<<dim3(BB * NH, SQ / 128), blk, 0, stream>>>(qh, kh, vth, attn, ctxh);

  proj_gemm_k<<<dim3(D_M / 128, TOK / 64), blk, 0, stream>>>(
      ctxh, WoT, bo, resid, TOK, D_M, D_M);
  add_ln_kernel<1><<<dim3(TOK), blk, 0, stream>>>(x, resid, g1, be1, x1b, x1c_h);

  convert2_bf16_k<<<dim3(n4_act / 256, 2), blk, 0, stream>>>(W1, W1c_h, W2, W2c_h, n4_act);
  ff_bf16_k<<<dim3(NH, TOK / 128), blk, 0, stream>>>(x1c_h, W1c_h, b1, W2c_h, b2, ffb);
  add_ln_kernel<0><<<dim3(TOK), blk, 0, stream>>>(x1b, ffb, g2, be2, y_out, nullptr);
}